// Round 4
// baseline (483.431 us; speedup 1.0000x reference)
//
#include <hip/hip_runtime.h>
#include <math.h>

typedef short bf16x8 __attribute__((ext_vector_type(8)));
typedef float f32x4  __attribute__((ext_vector_type(4)));

#define GLOAD_LDS16(SRC, DST) \
  __builtin_amdgcn_global_load_lds((const __attribute__((address_space(1))) void*)(SRC), \
      (__attribute__((address_space(3))) void*)(DST), 16, 0, 0)

#define WAITVM(N) asm volatile("s_waitcnt vmcnt(" #N ")" ::: "memory")
#define WAITLGKM0 asm volatile("s_waitcnt lgkmcnt(0)" ::: "memory")
#define BARRIER() do { __builtin_amdgcn_s_barrier(); asm volatile("" ::: "memory"); } while (0)

__device__ __forceinline__ unsigned short f2bf(float f) {
  union { float f; unsigned u; } v; v.f = f;
  unsigned r = v.u + 0x7FFFu + ((v.u >> 16) & 1u);   // RNE
  return (unsigned short)(r >> 16);
}
__device__ __forceinline__ float bf2f(unsigned short s) {
  union { unsigned u; float f; } v; v.u = ((unsigned)s) << 16;
  return v.f;
}
__device__ __forceinline__ unsigned pk2bf(float lo, float hi) {
  unsigned r;
  asm("v_cvt_pk_bf16_f32 %0, %1, %2" : "=v"(r) : "v"(lo), "v"(hi));  // RNE, lo->[15:0]
  return r;
}

// ---------------- weight conversion: W1T[j][k]=W1[k][j]; WabT[2d+p][k]=Wa/Wb[k][d]
__global__ void carp_wconv(const float* __restrict__ W1, const float* __restrict__ Wa,
                           const float* __restrict__ Wb,
                           unsigned short* __restrict__ W1T, unsigned short* __restrict__ WabT) {
  int idx = blockIdx.x * 256 + threadIdx.x;   // idx = j*512 + k
  int j = idx >> 9;
  int k = idx & 511;
  W1T[idx] = f2bf(W1[k * 512 + j]);
  int d = j >> 1;
  const float* Wx = (j & 1) ? Wb : Wa;
  WabT[idx] = f2bf(Wx[k * 256 + d]);
}

// LDS layout: fragment-linear granules. granule (16B) holds row=s*16+(l&15), k8=(l>>4)*8.
// Frag read = 64 lanes x contiguous 16B -> zero conflicts (verified R3: SQ_LDS_BANK_CONFLICT=0).

// ---------------- GEMM1: h1 = relu(h @ W1 + b1)
// BK=32, NBUF=3, depth-2 counted-vmcnt pipeline. A: fp32->regs->cvt->LDS (write-late). B: gload_lds.
__launch_bounds__(256)
__global__ void carp_gemm1(const float* __restrict__ h, const unsigned short* __restrict__ W1T,
                           const float* __restrict__ b1, unsigned short* __restrict__ h1) {
  __shared__ unsigned short As[3][128 * 32];
  __shared__ unsigned short Bs[3][128 * 32];
  int bid0 = blockIdx.x;
  int bid = (bid0 & 7) * 512 + (bid0 >> 3);   // XCD-contiguous remap (4096 = 8*512)
  int bn = bid & 3, bm = bid >> 2;
  int brow = bm * 128, bcol = bn * 128;
  int tid = threadIdx.x, lane = tid & 63, wid = tid >> 6;
  int wr = wid >> 1, wc = wid & 1;

  f32x4 acc[4][4] = {};
  float4 ar[2][4];   // A-reg staging, slot = tile&1 (all indices static after unroll)

#define G1_LOADA(T, SLOT) do { \
  _Pragma("unroll") for (int i = 0; i < 4; ++i) { \
    int f = i * 256 + tid; int g = f >> 1, half = f & 1; int s = g >> 6, l = g & 63; \
    int row = s * 16 + (l & 15), k8 = (l >> 4) * 8 + half * 4; \
    ar[SLOT][i] = *(const float4*)(h + (size_t)(brow + row) * 512 + (T) * 32 + k8); \
  } } while (0)
#define G1_WRITEA(T, SLOT) do { \
  unsigned short* dstA = As[(T) % 3]; \
  _Pragma("unroll") for (int i = 0; i < 4; ++i) { \
    int f = i * 256 + tid; \
    uint2 w; w.x = pk2bf(ar[SLOT][i].x, ar[SLOT][i].y); w.y = pk2bf(ar[SLOT][i].z, ar[SLOT][i].w); \
    *(uint2*)((char*)dstA + (size_t)f * 8) = w; \
  } } while (0)
#define G1_STAGEB(T, BUF) do { \
  _Pragma("unroll") for (int q = 0; q < 2; ++q) { \
    int s = wid * 2 + q; int row = s * 16 + (lane & 15), k8 = (lane >> 4) * 8; \
    GLOAD_LDS16(W1T + (size_t)(bcol + row) * 512 + (T) * 32 + k8, (char*)Bs[BUF] + (size_t)s * 1024); \
  } } while (0)

  // prologue: FIFO = A0(4) B0(2) A1(4) B1(2); wait 8 -> A0 done
  G1_LOADA(0, 0); G1_STAGEB(0, 0);
  G1_LOADA(1, 1); G1_STAGEB(1, 1);
  WAITVM(8);
  G1_WRITEA(0, 0);
  WAITLGKM0;

#pragma unroll
  for (int kt = 0; kt < 16; ++kt) {
    if (kt <= 13) { G1_LOADA(kt + 2, (kt & 1)); G1_STAGEB(kt + 2, (kt + 2) % 3); }
    // steady FIFO after issue: B(kt)2 A(kt+1)4 B(kt+1)2 A(kt+2)4 B(kt+2)2 = 14 -> leave 8
    if (kt <= 13) { WAITVM(8); } else if (kt == 14) { WAITVM(2); } else { WAITVM(0); }
    BARRIER();                                 // publish tile kt (A written last iter, B vmcnt'd)
    if (kt <= 14) G1_WRITEA(kt + 1, ((kt + 1) & 1));
    const char* Ab = (const char*)As[kt % 3];
    const char* Bb = (const char*)Bs[kt % 3];
    bf16x8 afr[4], bfr[4];
#pragma unroll
    for (int m = 0; m < 4; ++m)
      afr[m] = *(const bf16x8*)(Ab + (size_t)((wr * 4 + m) * 64 + lane) * 16);
#pragma unroll
    for (int n = 0; n < 4; ++n)
      bfr[n] = *(const bf16x8*)(Bb + (size_t)((wc * 4 + n) * 64 + lane) * 16);
#pragma unroll
    for (int m = 0; m < 4; ++m)
#pragma unroll
      for (int n = 0; n < 4; ++n)
        acc[m][n] = __builtin_amdgcn_mfma_f32_16x16x32_bf16(afr[m], bfr[n], acc[m][n], 0, 0, 0);
    WAITLGKM0;                                 // frag reads + A-writes complete
    BARRIER();                                 // safe to overwrite buffers next iter
  }
#undef G1_LOADA
#undef G1_WRITEA
#undef G1_STAGEB

  // epilogue: +b1, relu, bf16 store.  C map: col=lane&15, row=(lane>>4)*4+j
#pragma unroll
  for (int n = 0; n < 4; ++n) {
    int cg = bcol + wc * 64 + n * 16 + (lane & 15);
    float bias = b1[cg];
#pragma unroll
    for (int m = 0; m < 4; ++m) {
      int rbase = brow + wr * 64 + m * 16 + (lane >> 4) * 4;
#pragma unroll
      for (int j = 0; j < 4; ++j) {
        float v = acc[m][n][j] + bias;
        v = v > 0.f ? v : 0.f;
        h1[(size_t)(rbase + j) * 512 + cg] = f2bf(v);
      }
    }
  }
}

// ---------------- GEMM2: preact = h1 @ Wab_interleaved
// BK=64, NBUF=2, depth-1 counted-vmcnt pipeline; both operands bf16 via gload_lds.
__launch_bounds__(256)
__global__ void carp_gemm2(const unsigned short* __restrict__ h1, const unsigned short* __restrict__ WabT,
                           const float* __restrict__ ba, const float* __restrict__ bb,
                           const float* __restrict__ Wc, float* __restrict__ A_part) {
  __shared__ unsigned short As[2][128 * 64];
  __shared__ unsigned short Bs[2][128 * 64];
  int bid0 = blockIdx.x;
  int bid = (bid0 & 7) * 512 + (bid0 >> 3);   // XCD-contiguous remap
  int bn = bid & 3, bm = bid >> 2;
  int brow = bm * 128, bcol = bn * 128;
  int tid = threadIdx.x, lane = tid & 63, wid = tid >> 6;
  int wr = wid >> 1, wc = wid & 1;

  f32x4 acc[4][4] = {};

  // tile = 128 rows x 64 k; 16 chunks of 1KB; chunk c: s=c>>1 (row-subtile), t=c&1 (k-half)
#define G2_STAGE(T, BUF) do { \
  _Pragma("unroll") for (int j = 0; j < 4; ++j) { \
    int c = wid * 4 + j; \
    int row = (c >> 1) * 16 + (lane & 15); \
    int k = (T) * 64 + (c & 1) * 32 + (lane >> 4) * 8; \
    GLOAD_LDS16(h1 + (size_t)(brow + row) * 512 + k, (char*)As[BUF] + (size_t)c * 1024); \
    GLOAD_LDS16(WabT + (size_t)(bcol + row) * 512 + k, (char*)Bs[BUF] + (size_t)c * 1024); \
  } } while (0)

  G2_STAGE(0, 0);    // 8 ops outstanding

#pragma unroll
  for (int kt = 0; kt < 8; ++kt) {
    if (kt < 7) G2_STAGE(kt + 1, (kt + 1) & 1);   // -> 16 outstanding
    if (kt < 7) { WAITVM(8); } else { WAITVM(0); }  // tile kt landed, next stays in flight
    BARRIER();
    const char* Ab = (const char*)As[kt & 1];
    const char* Bb = (const char*)Bs[kt & 1];
#pragma unroll
    for (int t = 0; t < 2; ++t) {               // two K=32 slices
      bf16x8 afr[4], bfr[4];
#pragma unroll
      for (int m = 0; m < 4; ++m)
        afr[m] = *(const bf16x8*)(Ab + (size_t)(((wr * 4 + m) * 2 + t) * 64 + lane) * 16);
#pragma unroll
      for (int n = 0; n < 4; ++n)
        bfr[n] = *(const bf16x8*)(Bb + (size_t)(((wc * 4 + n) * 2 + t) * 64 + lane) * 16);
#pragma unroll
      for (int m = 0; m < 4; ++m)
#pragma unroll
        for (int n = 0; n < 4; ++n)
          acc[m][n] = __builtin_amdgcn_mfma_f32_16x16x32_bf16(afr[m], bfr[n], acc[m][n], 0, 0, 0);
    }
    WAITLGKM0;
    BARRIER();
  }
#undef G2_STAGE

  // epilogue: interleaved cols -> even lane = a-preact, odd lane = g-preact (same d)
  float rowpart[4][4] = {};                // [m][j]
#pragma unroll
  for (int n = 0; n < 4; ++n) {
    int cg = bcol + wc * 64 + n * 16 + (lane & 15);
    int d = cg >> 1;
    float bias = (cg & 1) ? bb[d] : ba[d];
    float wcd = Wc[d];
#pragma unroll
    for (int m = 0; m < 4; ++m)
#pragma unroll
      for (int j = 0; j < 4; ++j) {
        float v = acc[m][n][j] + bias;
        float av = (cg & 1) ? (1.f / (1.f + expf(-v))) : tanhf(v);
        float pv = av * __shfl_xor(av, 1, 64);   // a*g on both lanes of the pair
        rowpart[m][j] += pv * wcd;
      }
  }
#pragma unroll
  for (int m = 0; m < 4; ++m)
#pragma unroll
    for (int j = 0; j < 4; ++j) {
      float t = rowpart[m][j];
      t += __shfl_xor(t, 2, 64);
      t += __shfl_xor(t, 4, 64);
      t += __shfl_xor(t, 8, 64);
      rowpart[m][j] = t;
    }
  if ((lane & 15) == 0) {
    int slot = bn * 2 + wc;
#pragma unroll
    for (int m = 0; m < 4; ++m)
#pragma unroll
      for (int j = 0; j < 4; ++j) {
        int row = brow + wr * 64 + m * 16 + (lane >> 4) * 4 + j;
        A_part[(size_t)row * 8 + slot] = rowpart[m][j];
      }
  }
}

// ---------------- per-bag: A = sum(partials)+bc ; write A_raw ; softmax -> A_sm
__global__ void carp_softmax(const float* __restrict__ A_part, const float* __restrict__ bc,
                             float* __restrict__ A_raw_out, float* __restrict__ A_sm) {
  __shared__ float sv[8192];
  __shared__ float red[256];
  int b = blockIdx.x, tid = threadIdx.x;
  float bcv = bc[0];
  float lmax = -1e30f;
  for (int i = tid; i < 8192; i += 256) {
    const float4* p = (const float4*)(A_part + (size_t)(b * 8192 + i) * 8);
    float4 x = p[0], y = p[1];
    float s = ((x.x + x.y) + (x.z + x.w)) + ((y.x + y.y) + (y.z + y.w)) + bcv;
    sv[i] = s;
    A_raw_out[b * 8192 + i] = s;
    lmax = fmaxf(lmax, s);
  }
  red[tid] = lmax;
  for (int s = 128; s > 0; s >>= 1) { __syncthreads(); if (tid < s) red[tid] = fmaxf(red[tid], red[tid + s]); }
  __syncthreads();
  float mx = red[0];
  __syncthreads();
  float lsum = 0.f;
  for (int i = tid; i < 8192; i += 256) {
    float e = expf(sv[i] - mx);
    sv[i] = e;
    lsum += e;
  }
  red[tid] = lsum;
  for (int s = 128; s > 0; s >>= 1) { __syncthreads(); if (tid < s) red[tid] += red[tid + s]; }
  __syncthreads();
  float inv = 1.f / red[0];
  for (int i = tid; i < 8192; i += 256) A_sm[b * 8192 + i] = sv[i] * inv;
}

// ---------------- M partials: Mpart[b][sp][h] = sum_{n in chunk} A_sm[b][n]*h1[b,n,h]
__global__ void carp_mkernel(const unsigned short* __restrict__ h1, const float* __restrict__ A_sm,
                             float* __restrict__ Mpart) {
  __shared__ float sw[256];
  int b = blockIdx.x >> 5, sp = blockIdx.x & 31;
  int tid = threadIdx.x;
  int n0 = sp * 256;
  sw[tid] = A_sm[b * 8192 + n0 + tid];
  __syncthreads();
  float a0 = 0.f, a1 = 0.f;
  const unsigned short* base = h1 + ((size_t)(b * 8192 + n0)) * 512 + tid * 2;
  for (int i = 0; i < 256; ++i) {
    unsigned pv = *(const unsigned*)(base + (size_t)i * 512);
    float w = sw[i];
    a0 += w * bf2f((unsigned short)(pv & 0xFFFFu));
    a1 += w * bf2f((unsigned short)(pv >> 16));
  }
  float* mp = Mpart + ((size_t)(b * 32 + sp)) * 512 + tid * 2;
  mp[0] = a0; mp[1] = a1;
}

// ---------------- final: M out, context=mean, logits, softmax, argmax
__global__ void carp_final(const float* __restrict__ Mpart, const float* __restrict__ Wcls,
                           const float* __restrict__ bcls, float* __restrict__ out) {
  __shared__ float ctx[512];
  int t = threadIdx.x;   // 512 threads
  float c = 0.f;
  for (int b = 0; b < 16; ++b) {
    float s = 0.f;
    for (int sp = 0; sp < 32; ++sp) s += Mpart[((size_t)(b * 32 + sp) << 9) + t];
    out[131077 + b * 512 + t] = s;          // M  [16,1,512]
    c += s;
  }
  ctx[t] = c * (1.f / 16.f);
  __syncthreads();
  if (t < 64) {
    float p0 = 0.f, p1 = 0.f;
    for (int hh = t; hh < 512; hh += 64) {
      float cv = ctx[hh];
      p0 += cv * Wcls[hh * 2];
      p1 += cv * Wcls[hh * 2 + 1];
    }
    for (int m = 1; m < 64; m <<= 1) { p0 += __shfl_xor(p0, m, 64); p1 += __shfl_xor(p1, m, 64); }
    if (t == 0) {
      float l0 = p0 + bcls[0], l1 = p1 + bcls[1];
      out[0] = l0; out[1] = l1;
      float mx = fmaxf(l0, l1);
      float e0 = expf(l0 - mx), e1 = expf(l1 - mx);
      float s = e0 + e1;
      out[2] = e0 / s; out[3] = e1 / s;
      out[4] = (l1 > l0) ? 1.0f : 0.0f;     // argmax (first-max tie -> 0)
    }
  }
}

extern "C" void kernel_launch(void* const* d_in, const int* in_sizes, int n_in,
                              void* d_out, int out_size, void* d_ws, size_t ws_size,
                              hipStream_t stream) {
  const float* h    = (const float*)d_in[0];
  const float* W1   = (const float*)d_in[1];
  const float* b1   = (const float*)d_in[2];
  const float* Wa   = (const float*)d_in[3];
  const float* ba   = (const float*)d_in[4];
  const float* Wb   = (const float*)d_in[5];
  const float* bb   = (const float*)d_in[6];
  const float* Wc   = (const float*)d_in[7];
  const float* bc   = (const float*)d_in[8];
  const float* Wcls = (const float*)d_in[9];
  const float* bcls = (const float*)d_in[10];
  float* out = (float*)d_out;

  char* ws = (char*)d_ws;
  unsigned short* h1   = (unsigned short*)(ws);                     // 134,217,728 B
  unsigned short* W1T  = (unsigned short*)(ws + 134217728);         //     524,288 B
  unsigned short* WabT = (unsigned short*)(ws + 134742016);         //     524,288 B
  float* A_part        = (float*)(ws + 135266304);                  //   4,194,304 B
  float* A_sm          = (float*)(ws + 139460608);                  //     524,288 B
  float* Mpart         = (float*)(ws + 139984896);                  //   1,048,576 B -> total 141,033,472 B

  carp_wconv  <<<1024, 256, 0, stream>>>(W1, Wa, Wb, W1T, WabT);
  carp_gemm1  <<<4096, 256, 0, stream>>>(h, W1T, b1, h1);
  carp_gemm2  <<<4096, 256, 0, stream>>>(h1, WabT, ba, bb, Wc, A_part);
  carp_softmax<<<16,   256, 0, stream>>>(A_part, bc, out + 5, A_sm);
  carp_mkernel<<<512,  256, 0, stream>>>(h1, A_sm, Mpart);
  carp_final  <<<1,    512, 0, stream>>>(Mpart, Wcls, bcls, out);
}

// Round 5
// 442.926 us; speedup vs baseline: 1.0914x; 1.0914x over previous
//
#include <hip/hip_runtime.h>
#include <math.h>

typedef short bf16x8 __attribute__((ext_vector_type(8)));
typedef float f32x4  __attribute__((ext_vector_type(4)));

#define GLOAD_LDS16(SRC, DST) \
  __builtin_amdgcn_global_load_lds((const __attribute__((address_space(1))) void*)(SRC), \
      (__attribute__((address_space(3))) void*)(DST), 16, 0, 0)

#define WAITVM(N) asm volatile("s_waitcnt vmcnt(" #N ")" ::: "memory")
#define WAITLGKM0 asm volatile("s_waitcnt lgkmcnt(0)" ::: "memory")
#define BARRIER() do { __builtin_amdgcn_s_barrier(); asm volatile("" ::: "memory"); } while (0)

__device__ __forceinline__ unsigned short f2bf(float f) {
  union { float f; unsigned u; } v; v.f = f;
  unsigned r = v.u + 0x7FFFu + ((v.u >> 16) & 1u);   // RNE
  return (unsigned short)(r >> 16);
}
__device__ __forceinline__ float bf2f(unsigned short s) {
  union { unsigned u; float f; } v; v.u = ((unsigned)s) << 16;
  return v.f;
}
__device__ __forceinline__ unsigned pk2bf(float lo, float hi) {
  unsigned r;
  asm("v_cvt_pk_bf16_f32 %0, %1, %2" : "=v"(r) : "v"(lo), "v"(hi));  // RNE, lo->[15:0]
  return r;
}

// Packed-tile layout ("granule"): a [128 rows x 32 k] bf16 tile = 512 granules of 16B.
// granule g = s*64 + l: row = s*16 + (l&15), k8 = (l>>4)*8 (8 consecutive k).
// Tile t of panel p lives at granule offset (p*16 + t)*512. Staging a tile is
// contiguous 1KB-per-wave gload_lds; MFMA frag read = granule (s*64+lane) = linear.

// ---------------- weight pack: W1T_pk / WabT_pk in granule layout
__global__ void carp_wpack(const float* __restrict__ W1, const float* __restrict__ Wa,
                           const float* __restrict__ Wb,
                           unsigned short* __restrict__ W1T_pk, unsigned short* __restrict__ WabT_pk) {
  int t = blockIdx.x * 256 + threadIdx.x;     // 0..65535
  int mat = t >> 15;                          // 0: W1, 1: Wab
  int gid = t & 32767;                        // granule id: p(2) kt(4) g(9)
  int g = gid & 511;
  int kt = (gid >> 9) & 15;
  int p = gid >> 13;
  int s = g >> 6, l = g & 63;
  int j = p * 128 + s * 16 + (l & 15);        // output column (H dim)
  int k = kt * 32 + (l >> 4) * 8;             // K base
  unsigned short v[8];
  if (mat == 0) {
#pragma unroll
    for (int e = 0; e < 8; ++e) v[e] = f2bf(W1[(size_t)(k + e) * 512 + j]);
    *(uint4*)(W1T_pk + (size_t)gid * 8) = *(const uint4*)v;
  } else {
    int d = j >> 1;
    const float* Wx = (j & 1) ? Wb : Wa;
#pragma unroll
    for (int e = 0; e < 8; ++e) v[e] = f2bf(Wx[(size_t)(k + e) * 256 + d]);
    *(uint4*)(WabT_pk + (size_t)gid * 8) = *(const uint4*)v;
  }
}

// ---------------- GEMM1: h1 = relu(h @ W1 + b1), BK=64
// A: fp32 row-contiguous loads -> regs -> cvt_pk -> granule ds_write (depth-2).
// B: packed gload_lds (depth-1). Output: h1_pk granule layout via LDS bounce.
__launch_bounds__(256)
__global__ void carp_gemm1(const float* __restrict__ h, const unsigned short* __restrict__ W1T_pk,
                           const float* __restrict__ b1, unsigned short* __restrict__ h1_pk) {
  __shared__ unsigned short As[2][8192];   // 16KB per buf (2 packed 32k-tiles)
  __shared__ unsigned short Bs[2][8192];
  int bid0 = blockIdx.x;
  int bid = (bid0 & 7) * 512 + (bid0 >> 3);   // XCD-contiguous remap (4096 = 8*512)
  int bn = bid & 3, bm = bid >> 2;
  int brow = bm * 128, bcol = bn * 128;
  int tid = threadIdx.x, lane = tid & 63, wid = tid >> 6;
  int wr = wid >> 1, wc = wid & 1;

  f32x4 acc[4][4] = {};
  float4 ar[2][8];

  // thread t owns rows j*16 + (t>>4) (j=0..7), col-chunk (t&15)*4 of the 64-k tile
  int arow_lo = tid >> 4;        // row within 16-row group
  int ac = tid & 15;             // 4-float col chunk, cols 4c..4c+3
  // granule ds_write target pieces (static per thread):
  int att = ac >> 3;                               // which 32k tile
  int al16 = arow_lo + ((ac & 7) >> 1) * 16;       // l minus row-subtile part
  int abyte_half = (ac & 1) * 8;

#define G1_LOADA(T, SLOT) do { \
  _Pragma("unroll") for (int j = 0; j < 8; ++j) { \
    int row = j * 16 + arow_lo; \
    ar[SLOT][j] = *(const float4*)(h + (size_t)(brow + row) * 512 + (T) * 64 + ac * 4); \
  } } while (0)
#define G1_WRITEA(T) do { \
  unsigned short* dstA = As[(T) & 1]; \
  _Pragma("unroll") for (int j = 0; j < 8; ++j) { \
    uint2 w; \
    w.x = pk2bf(ar[(T) & 1][j].x, ar[(T) & 1][j].y); \
    w.y = pk2bf(ar[(T) & 1][j].z, ar[(T) & 1][j].w); \
    *(uint2*)((char*)dstA + att * 8192 + (size_t)(j * 64 + al16) * 16 + abyte_half) = w; \
  } } while (0)
#define G1_STAGEB(T, BUF) do { \
  _Pragma("unroll") for (int q = 0; q < 4; ++q) { \
    int c = wid * 4 + q; \
    const unsigned short* src = W1T_pk + \
      ((size_t)(bn * 16 + 2 * (T) + (c >> 3)) * 512 + (c & 7) * 64 + lane) * 8; \
    GLOAD_LDS16(src, (char*)Bs[BUF] + (size_t)c * 1024); \
  } } while (0)

  // prologue: FIFO = A0(8) B0(4) A1(8); wait 12 -> A0 done
  G1_LOADA(0, 0); G1_STAGEB(0, 0); G1_LOADA(1, 1);
  WAITVM(12);
  G1_WRITEA(0);
  WAITLGKM0;

#pragma unroll
  for (int kt = 0; kt < 8; ++kt) {
    if (kt <= 5) G1_LOADA(kt + 2, (kt & 1));
    if (kt <= 6) G1_STAGEB(kt + 1, (kt + 1) & 1);
    // steady queue after issue: B(kt)4 A(kt+1)8 A(kt+2)8 B(kt+1)4 -> leave 12
    if (kt <= 5) { WAITVM(12); } else if (kt == 6) { WAITVM(4); } else { WAITVM(0); }
    BARRIER();                                 // tile kt published
    if (kt <= 6) G1_WRITEA(kt + 1);
    const char* Ab = (const char*)As[kt & 1];
    const char* Bb = (const char*)Bs[kt & 1];
#pragma unroll
    for (int tt = 0; tt < 2; ++tt) {
      bf16x8 afr[4], bfr[4];
#pragma unroll
      for (int m = 0; m < 4; ++m)
        afr[m] = *(const bf16x8*)(Ab + tt * 8192 + (size_t)((wr * 4 + m) * 64 + lane) * 16);
#pragma unroll
      for (int n = 0; n < 4; ++n)
        bfr[n] = *(const bf16x8*)(Bb + tt * 8192 + (size_t)((wc * 4 + n) * 64 + lane) * 16);
#pragma unroll
      for (int m = 0; m < 4; ++m)
#pragma unroll
        for (int n = 0; n < 4; ++n)
          acc[m][n] = __builtin_amdgcn_mfma_f32_16x16x32_bf16(afr[m], bfr[n], acc[m][n], 0, 0, 0);
    }
    WAITLGKM0;
    BARRIER();
  }
#undef G1_LOADA
#undef G1_WRITEA
#undef G1_STAGEB

  // epilogue: +b1, relu -> scatter bf16 into LDS granule image [128x128] -> contiguous store
  unsigned short* img = (unsigned short*)As;   // 32KB image
#pragma unroll
  for (int n = 0; n < 4; ++n) {
    int cl = wc * 64 + n * 16 + (lane & 15);   // local col 0..127
    float bias = b1[bcol + cl];
    int tt2 = cl >> 5;
    int lcol = cl & 31;
    size_t cbase = (size_t)tt2 * 8192 + ((size_t)(lcol >> 3) * 16) * 16 + (lcol & 7) * 2;
#pragma unroll
    for (int m = 0; m < 4; ++m) {
      int rbase = wr * 64 + m * 16 + (lane >> 4) * 4;
#pragma unroll
      for (int j = 0; j < 4; ++j) {
        int row = rbase + j;
        float v = acc[m][n][j] + bias;
        v = v > 0.f ? v : 0.f;
        *(unsigned short*)((char*)img + cbase + ((size_t)(row >> 4) * 64 + (row & 15)) * 16) = f2bf(v);
      }
    }
  }
  __syncthreads();
#pragma unroll
  for (int i = 0; i < 8; ++i) {
    int gidx = i * 256 + tid;                  // 0..2047 granules
    uint4 val = *(const uint4*)((const char*)img + (size_t)gidx * 16);
    *(uint4*)(h1_pk + ((size_t)(bm * 16 + bn * 4 + (gidx >> 9)) * 512 + (gidx & 511)) * 8) = val;
  }
}

// ---------------- GEMM2: preact = h1 @ Wab_interleaved, BK=64, pure packed gload_lds
__launch_bounds__(256)
__global__ void carp_gemm2(const unsigned short* __restrict__ h1_pk, const unsigned short* __restrict__ WabT_pk,
                           const float* __restrict__ ba, const float* __restrict__ bb,
                           const float* __restrict__ Wc, float* __restrict__ A_part) {
  __shared__ unsigned short As[2][8192];
  __shared__ unsigned short Bs[2][8192];
  int bid0 = blockIdx.x;
  int bid = (bid0 & 7) * 512 + (bid0 >> 3);
  int bn = bid & 3, bm = bid >> 2;
  int tid = threadIdx.x, lane = tid & 63, wid = tid >> 6;
  int wr = wid >> 1, wc = wid & 1;

  f32x4 acc[4][4] = {};

#define G2_STAGE(T, BUF) do { \
  _Pragma("unroll") for (int q = 0; q < 4; ++q) { \
    int c = wid * 4 + q; \
    size_t goff = ((size_t)(2 * (T) + (c >> 3)) * 512 + (c & 7) * 64 + lane) * 8; \
    GLOAD_LDS16(h1_pk + (size_t)(bm * 16) * 4096 + goff, (char*)As[BUF] + (size_t)c * 1024); \
    GLOAD_LDS16(WabT_pk + (size_t)(bn * 16) * 4096 + goff, (char*)Bs[BUF] + (size_t)c * 1024); \
  } } while (0)

  G2_STAGE(0, 0);    // 8 outstanding

#pragma unroll
  for (int kt = 0; kt < 8; ++kt) {
    if (kt < 7) G2_STAGE(kt + 1, (kt + 1) & 1);   // -> 16 outstanding
    if (kt < 7) { WAITVM(8); } else { WAITVM(0); }
    BARRIER();
    const char* Ab = (const char*)As[kt & 1];
    const char* Bb = (const char*)Bs[kt & 1];
#pragma unroll
    for (int tt = 0; tt < 2; ++tt) {
      bf16x8 afr[4], bfr[4];
#pragma unroll
      for (int m = 0; m < 4; ++m)
        afr[m] = *(const bf16x8*)(Ab + tt * 8192 + (size_t)((wr * 4 + m) * 64 + lane) * 16);
#pragma unroll
      for (int n = 0; n < 4; ++n)
        bfr[n] = *(const bf16x8*)(Bb + tt * 8192 + (size_t)((wc * 4 + n) * 64 + lane) * 16);
#pragma unroll
      for (int m = 0; m < 4; ++m)
#pragma unroll
        for (int n = 0; n < 4; ++n)
          acc[m][n] = __builtin_amdgcn_mfma_f32_16x16x32_bf16(afr[m], bfr[n], acc[m][n], 0, 0, 0);
    }
    WAITLGKM0;
    BARRIER();
  }
#undef G2_STAGE

  int brow = bm * 128, bcol = bn * 128;
  // epilogue: interleaved cols -> even lane = a-preact, odd lane = g-preact (same d)
  float rowpart[4][4] = {};                // [m][j]
#pragma unroll
  for (int n = 0; n < 4; ++n) {
    int cg = bcol + wc * 64 + n * 16 + (lane & 15);
    int d = cg >> 1;
    float bias = (cg & 1) ? bb[d] : ba[d];
    float wcd = Wc[d];
#pragma unroll
    for (int m = 0; m < 4; ++m)
#pragma unroll
      for (int j = 0; j < 4; ++j) {
        float v = acc[m][n][j] + bias;
        float av = (cg & 1) ? (1.f / (1.f + expf(-v))) : tanhf(v);
        float pv = av * __shfl_xor(av, 1, 64);   // a*g on both lanes of the pair
        rowpart[m][j] += pv * wcd;
      }
  }
#pragma unroll
  for (int m = 0; m < 4; ++m)
#pragma unroll
    for (int j = 0; j < 4; ++j) {
      float t = rowpart[m][j];
      t += __shfl_xor(t, 2, 64);
      t += __shfl_xor(t, 4, 64);
      t += __shfl_xor(t, 8, 64);
      rowpart[m][j] = t;
    }
  if ((lane & 15) == 0) {
    int slot = bn * 2 + wc;
#pragma unroll
    for (int m = 0; m < 4; ++m)
#pragma unroll
      for (int j = 0; j < 4; ++j) {
        int row = brow + wr * 64 + m * 16 + (lane >> 4) * 4 + j;
        A_part[(size_t)row * 8 + slot] = rowpart[m][j];
      }
  }
}

// ---------------- per-bag: A = sum(partials)+bc ; write A_raw ; softmax -> A_sm
__global__ void carp_softmax(const float* __restrict__ A_part, const float* __restrict__ bc,
                             float* __restrict__ A_raw_out, float* __restrict__ A_sm) {
  __shared__ float sv[8192];
  __shared__ float red[256];
  int b = blockIdx.x, tid = threadIdx.x;
  float bcv = bc[0];
  float lmax = -1e30f;
  for (int i = tid; i < 8192; i += 256) {
    const float4* p = (const float4*)(A_part + (size_t)(b * 8192 + i) * 8);
    float4 x = p[0], y = p[1];
    float s = ((x.x + x.y) + (x.z + x.w)) + ((y.x + y.y) + (y.z + y.w)) + bcv;
    sv[i] = s;
    A_raw_out[b * 8192 + i] = s;
    lmax = fmaxf(lmax, s);
  }
  red[tid] = lmax;
  for (int s = 128; s > 0; s >>= 1) { __syncthreads(); if (tid < s) red[tid] = fmaxf(red[tid], red[tid + s]); }
  __syncthreads();
  float mx = red[0];
  __syncthreads();
  float lsum = 0.f;
  for (int i = tid; i < 8192; i += 256) {
    float e = expf(sv[i] - mx);
    sv[i] = e;
    lsum += e;
  }
  red[tid] = lsum;
  for (int s = 128; s > 0; s >>= 1) { __syncthreads(); if (tid < s) red[tid] += red[tid + s]; }
  __syncthreads();
  float inv = 1.f / red[0];
  for (int i = tid; i < 8192; i += 256) A_sm[b * 8192 + i] = sv[i] * inv;
}

// ---------------- M partials from packed h1: block = one 128-row panel (bm)
// Mpart[bm][hcol] = sum_{rows in panel} A_sm[row] * h1[row][hcol]
__global__ void carp_mkernel(const unsigned short* __restrict__ h1_pk, const float* __restrict__ A_sm,
                             float* __restrict__ Mpart) {
  __shared__ float sw[128];
  int bm = blockIdx.x;
  int tid = threadIdx.x;
  if (tid < 128) sw[tid] = A_sm[bm * 128 + tid];
  __syncthreads();
  int l = tid & 63;
  float acc[4][8] = {};
#pragma unroll
  for (int tq = 0; tq < 4; ++tq) {
    int tt = (tid >> 6) * 4 + tq;
#pragma unroll
    for (int s = 0; s < 8; ++s) {
      const unsigned short* gp = h1_pk + ((size_t)(bm * 16 + tt) * 512 + s * 64 + l) * 8;
      uint4 raw = *(const uint4*)gp;           // contiguous 1KB per wave
      const unsigned short* pv = (const unsigned short*)&raw;
      float w = sw[s * 16 + (l & 15)];
#pragma unroll
      for (int e = 0; e < 8; ++e) acc[tq][e] += w * bf2f(pv[e]);
    }
  }
  // reduce over the 16-lane group (same cols, different rows)
#pragma unroll
  for (int tq = 0; tq < 4; ++tq)
#pragma unroll
    for (int e = 0; e < 8; ++e) {
      float t = acc[tq][e];
      t += __shfl_xor(t, 1, 64);
      t += __shfl_xor(t, 2, 64);
      t += __shfl_xor(t, 4, 64);
      t += __shfl_xor(t, 8, 64);
      acc[tq][e] = t;
    }
  if ((l & 15) == 0) {
    int cc = (l >> 4) & 3;
#pragma unroll
    for (int tq = 0; tq < 4; ++tq) {
      int tt = (tid >> 6) * 4 + tq;
      float* mp = Mpart + (size_t)bm * 512 + tt * 32 + cc * 8;
#pragma unroll
      for (int e = 0; e < 8; ++e) mp[e] = acc[tq][e];
    }
  }
}

// ---------------- final: M out (sum 64 panels/bag), context=mean, logits, softmax, argmax
__global__ void carp_final(const float* __restrict__ Mpart, const float* __restrict__ Wcls,
                           const float* __restrict__ bcls, float* __restrict__ out) {
  __shared__ float ctx[512];
  int t = threadIdx.x;   // 512 threads
  float c = 0.f;
  for (int b = 0; b < 16; ++b) {
    float s = 0.f;
    for (int p = 0; p < 64; ++p) s += Mpart[((size_t)(b * 64 + p) << 9) + t];
    out[131077 + b * 512 + t] = s;          // M  [16,1,512]
    c += s;
  }
  ctx[t] = c * (1.f / 16.f);
  __syncthreads();
  if (t < 64) {
    float p0 = 0.f, p1 = 0.f;
    for (int hh = t; hh < 512; hh += 64) {
      float cv = ctx[hh];
      p0 += cv * Wcls[hh * 2];
      p1 += cv * Wcls[hh * 2 + 1];
    }
    for (int m = 1; m < 64; m <<= 1) { p0 += __shfl_xor(p0, m, 64); p1 += __shfl_xor(p1, m, 64); }
    if (t == 0) {
      float l0 = p0 + bcls[0], l1 = p1 + bcls[1];
      out[0] = l0; out[1] = l1;
      float mx = fmaxf(l0, l1);
      float e0 = expf(l0 - mx), e1 = expf(l1 - mx);
      float s = e0 + e1;
      out[2] = e0 / s; out[3] = e1 / s;
      out[4] = (l1 > l0) ? 1.0f : 0.0f;     // argmax (first-max tie -> 0)
    }
  }
}

extern "C" void kernel_launch(void* const* d_in, const int* in_sizes, int n_in,
                              void* d_out, int out_size, void* d_ws, size_t ws_size,
                              hipStream_t stream) {
  const float* h    = (const float*)d_in[0];
  const float* W1   = (const float*)d_in[1];
  const float* b1   = (const float*)d_in[2];
  const float* Wa   = (const float*)d_in[3];
  const float* ba   = (const float*)d_in[4];
  const float* Wb   = (const float*)d_in[5];
  const float* bb   = (const float*)d_in[6];
  const float* Wc   = (const float*)d_in[7];
  const float* bc   = (const float*)d_in[8];
  const float* Wcls = (const float*)d_in[9];
  const float* bcls = (const float*)d_in[10];
  float* out = (float*)d_out;

  char* ws = (char*)d_ws;
  unsigned short* h1_pk   = (unsigned short*)(ws);                  // 134,217,728 B
  unsigned short* W1T_pk  = (unsigned short*)(ws + 134217728);      //     524,288 B
  unsigned short* WabT_pk = (unsigned short*)(ws + 134742016);      //     524,288 B
  float* A_part           = (float*)(ws + 135266304);               //   4,194,304 B
  float* A_sm             = (float*)(ws + 139460608);               //     524,288 B
  float* Mpart            = (float*)(ws + 135266304);               //   2 MB, overlays A_part (used after softmax)

  carp_wpack  <<<256,  256, 0, stream>>>(W1, Wa, Wb, W1T_pk, WabT_pk);
  carp_gemm1  <<<4096, 256, 0, stream>>>(h, W1T_pk, b1, h1_pk);
  carp_gemm2  <<<4096, 256, 0, stream>>>(h1_pk, WabT_pk, ba, bb, Wc, A_part);
  carp_softmax<<<16,   256, 0, stream>>>(A_part, bc, out + 5, A_sm);
  carp_mkernel<<<1024, 256, 0, stream>>>(h1_pk, A_sm, Mpart);
  carp_final  <<<1,    512, 0, stream>>>(Mpart, Wcls, bcls, out);
}

// Round 6
// 389.614 us; speedup vs baseline: 1.2408x; 1.1368x over previous
//
#include <hip/hip_runtime.h>
#include <math.h>

typedef short bf16x8 __attribute__((ext_vector_type(8)));
typedef float f32x4  __attribute__((ext_vector_type(4)));

#define GLOAD_LDS16(SRC, DST) \
  __builtin_amdgcn_global_load_lds((const __attribute__((address_space(1))) void*)(SRC), \
      (__attribute__((address_space(3))) void*)(DST), 16, 0, 0)

#define WAITVM(N) asm volatile("s_waitcnt vmcnt(" #N ")" ::: "memory")
#define WAITLGKM0 asm volatile("s_waitcnt lgkmcnt(0)" ::: "memory")
#define BARRIER() do { __builtin_amdgcn_s_barrier(); asm volatile("" ::: "memory"); } while (0)

__device__ __forceinline__ unsigned short f2bf(float f) {
  union { float f; unsigned u; } v; v.f = f;
  unsigned r = v.u + 0x7FFFu + ((v.u >> 16) & 1u);   // RNE
  return (unsigned short)(r >> 16);
}
__device__ __forceinline__ float bf2f(unsigned short s) {
  union { unsigned u; float f; } v; v.u = ((unsigned)s) << 16;
  return v.f;
}
__device__ __forceinline__ unsigned pk2bf(float lo, float hi) {
  unsigned r;
  asm("v_cvt_pk_bf16_f32 %0, %1, %2" : "=v"(r) : "v"(lo), "v"(hi));  // RNE
  return r;
}

// Packed granule layout: [128 x 32k] bf16 tile = 512 granules of 16B.
// granule g = s*64 + l: row = s*16 + (l&15), k8 = (l>>4)*8.

// ---------------- weight pack (unchanged from R5)
__global__ void carp_wpack(const float* __restrict__ W1, const float* __restrict__ Wa,
                           const float* __restrict__ Wb,
                           unsigned short* __restrict__ W1T_pk, unsigned short* __restrict__ WabT_pk) {
  int t = blockIdx.x * 256 + threadIdx.x;
  int mat = t >> 15;
  int gid = t & 32767;
  int g = gid & 511;
  int kt = (gid >> 9) & 15;
  int p = gid >> 13;
  int s = g >> 6, l = g & 63;
  int j = p * 128 + s * 16 + (l & 15);
  int k = kt * 32 + (l >> 4) * 8;
  unsigned short v[8];
  if (mat == 0) {
#pragma unroll
    for (int e = 0; e < 8; ++e) v[e] = f2bf(W1[(size_t)(k + e) * 512 + j]);
    *(uint4*)(W1T_pk + (size_t)gid * 8) = *(const uint4*)v;
  } else {
    int d = j >> 1;
    const float* Wx = (j & 1) ? Wb : Wa;
#pragma unroll
    for (int e = 0; e < 8; ++e) v[e] = f2bf(Wx[(size_t)(k + e) * 256 + d]);
    *(uint4*)(WabT_pk + (size_t)gid * 8) = *(const uint4*)v;
  }
}

// ---------------- GEMM1: 8 waves, per-wave 32x64 out (acc=32 AGPR), BK=64
__launch_bounds__(512, 4)
__global__ void carp_gemm1(const float* __restrict__ h, const unsigned short* __restrict__ W1T_pk,
                           const float* __restrict__ b1, unsigned short* __restrict__ h1_pk) {
  __shared__ unsigned short As[2][8192];   // 16KB per buf
  __shared__ unsigned short Bs[2][8192];
  int bid0 = blockIdx.x;
  int bid = (bid0 & 7) * 512 + (bid0 >> 3);
  int bn = bid & 3, bm = bid >> 2;
  int brow = bm * 128;
  int tid = threadIdx.x, lane = tid & 63, wid = tid >> 6;
  int wr = wid >> 1, wc = wid & 1;         // 4x2 wave grid: 32 rows x 64 cols per wave

  f32x4 acc[2][4] = {};
  float4 arA[4], arB[4];

  // A staging: wave w loads rows 16w..16w+15; inst q: rows 16w+q*4+(lane>>4), cols (lane&15)*4
  const float* hbase = h + (size_t)(brow + wid * 16) * 512;
  int rq = lane >> 4;
  int cq = (lane & 15) * 4;
  // granule ds_write pieces
  int ttA = (lane & 15) >> 3;
  int colgrpA = ((lane & 15) >> 1) & 3;
  int halfA = lane & 1;
  int aoff = ttA * 8192 + wid * 1024 + colgrpA * 256 + rq * 16 + halfA * 8;

#define G1_LOADA(T, AR) do { \
  _Pragma("unroll") for (int q = 0; q < 4; ++q) \
    AR[q] = *(const float4*)(hbase + (size_t)(q * 4 + rq) * 512 + (T) * 64 + cq); \
  } while (0)
#define G1_WRITEA(T, AR) do { \
  char* dstA = (char*)As[(T) & 1] + aoff; \
  _Pragma("unroll") for (int q = 0; q < 4; ++q) { \
    uint2 wv; wv.x = pk2bf(AR[q].x, AR[q].y); wv.y = pk2bf(AR[q].z, AR[q].w); \
    *(uint2*)(dstA + q * 64) = wv; \
  } } while (0)
#define G1_STAGEB(T, BUF) do { \
  _Pragma("unroll") for (int q = 0; q < 2; ++q) { \
    int c = wid * 2 + q; \
    GLOAD_LDS16(W1T_pk + ((size_t)(bn * 16 + 2 * (T)) * 512 + c * 64 + lane) * 8, \
                (char*)Bs[BUF] + (size_t)c * 1024); \
  } } while (0)

  // prologue
  G1_STAGEB(0, 0);
  G1_LOADA(0, arA);
  G1_LOADA(1, arB);
  WAITVM(4);           // B0 + A0 done (A1 in flight)
  G1_WRITEA(0, arA);

#pragma unroll
  for (int kt = 0; kt < 8; ++kt) {
    if (kt + 1 < 8) G1_STAGEB(kt + 1, (kt + 1) & 1);
    if (kt + 2 < 8) { if (((kt + 2) & 1) == 0) G1_LOADA(kt + 2, arA); else G1_LOADA(kt + 2, arB); }
    if (kt <= 5) { WAITVM(6); } else if (kt == 6) { WAITVM(2); } else { WAITVM(0); }
    if (kt + 1 < 8) { if (((kt + 1) & 1) == 0) G1_WRITEA(kt + 1, arA); else G1_WRITEA(kt + 1, arB); }
    WAITLGKM0;
    BARRIER();                               // tile kt published
    const char* Ab = (const char*)As[kt & 1];
    const char* Bb = (const char*)Bs[kt & 1];
#pragma unroll
    for (int tt = 0; tt < 2; ++tt) {
      bf16x8 afr[2], bfr[4];
#pragma unroll
      for (int m = 0; m < 2; ++m)
        afr[m] = *(const bf16x8*)(Ab + tt * 8192 + (size_t)((wr * 2 + m) * 64 + lane) * 16);
#pragma unroll
      for (int n = 0; n < 4; ++n)
        bfr[n] = *(const bf16x8*)(Bb + tt * 8192 + (size_t)((wc * 4 + n) * 64 + lane) * 16);
#pragma unroll
      for (int m = 0; m < 2; ++m)
#pragma unroll
        for (int n = 0; n < 4; ++n)
          acc[m][n] = __builtin_amdgcn_mfma_f32_16x16x32_bf16(afr[m], bfr[n], acc[m][n], 0, 0, 0);
    }
    WAITLGKM0;
    BARRIER();                               // reads drained: buffers reusable
  }
#undef G1_LOADA
#undef G1_WRITEA
#undef G1_STAGEB

  // epilogue: +b1, relu -> LDS granule image -> contiguous h1_pk store
  unsigned short* img = (unsigned short*)As;   // 32KB
#pragma unroll
  for (int n = 0; n < 4; ++n) {
    int cl = wc * 64 + n * 16 + (lane & 15);
    float bias = b1[bn * 128 + cl];
    int ct = cl >> 5, colgrp = (cl & 31) >> 3, soff = cl & 7;
#pragma unroll
    for (int m = 0; m < 2; ++m)
#pragma unroll
      for (int j = 0; j < 4; ++j) {
        int rl = wr * 32 + m * 16 + (lane >> 4) * 4 + j;
        float v = acc[m][n][j] + bias;
        v = v > 0.f ? v : 0.f;
        img[((size_t)ct * 512 + (rl >> 4) * 64 + colgrp * 16 + (rl & 15)) * 8 + soff] = f2bf(v);
      }
  }
  __syncthreads();
  size_t gbase = (size_t)(bm * 16 + bn * 4) * 512;
#pragma unroll
  for (int i = 0; i < 4; ++i) {
    int g = i * 512 + tid;
    *(uint4*)(h1_pk + (gbase + g) * 8) = *(const uint4*)(img + (size_t)g * 8);
  }
}

// ---------------- GEMM2: 8 waves, per-wave 32x64, BK=64, packed gload_lds
__launch_bounds__(512, 4)
__global__ void carp_gemm2(const unsigned short* __restrict__ h1_pk, const unsigned short* __restrict__ WabT_pk,
                           const float* __restrict__ ba, const float* __restrict__ bb,
                           const float* __restrict__ Wc, float* __restrict__ A_part) {
  __shared__ unsigned short As[2][8192];
  __shared__ unsigned short Bs[2][8192];
  int bid0 = blockIdx.x;
  int bid = (bid0 & 7) * 512 + (bid0 >> 3);
  int bn = bid & 3, bm = bid >> 2;
  int tid = threadIdx.x, lane = tid & 63, wid = tid >> 6;
  int wr = wid >> 1, wc = wid & 1;

  f32x4 acc[2][4] = {};

#define G2_STAGE(T, BUF) do { \
  _Pragma("unroll") for (int q = 0; q < 2; ++q) { \
    int c = wid * 2 + q; \
    size_t goff = ((size_t)(2 * (T)) * 512 + c * 64 + lane) * 8; \
    GLOAD_LDS16(h1_pk + (size_t)(bm * 16) * 4096 + goff, (char*)As[BUF] + (size_t)c * 1024); \
    GLOAD_LDS16(WabT_pk + (size_t)(bn * 16) * 4096 + goff, (char*)Bs[BUF] + (size_t)c * 1024); \
  } } while (0)

  G2_STAGE(0, 0);

#pragma unroll
  for (int kt = 0; kt < 8; ++kt) {
    if (kt + 1 < 8) G2_STAGE(kt + 1, (kt + 1) & 1);
    if (kt < 7) { WAITVM(4); } else { WAITVM(0); }
    BARRIER();
    const char* Ab = (const char*)As[kt & 1];
    const char* Bb = (const char*)Bs[kt & 1];
#pragma unroll
    for (int tt = 0; tt < 2; ++tt) {
      bf16x8 afr[2], bfr[4];
#pragma unroll
      for (int m = 0; m < 2; ++m)
        afr[m] = *(const bf16x8*)(Ab + tt * 8192 + (size_t)((wr * 2 + m) * 64 + lane) * 16);
#pragma unroll
      for (int n = 0; n < 4; ++n)
        bfr[n] = *(const bf16x8*)(Bb + tt * 8192 + (size_t)((wc * 4 + n) * 64 + lane) * 16);
#pragma unroll
      for (int m = 0; m < 2; ++m)
#pragma unroll
        for (int n = 0; n < 4; ++n)
          acc[m][n] = __builtin_amdgcn_mfma_f32_16x16x32_bf16(afr[m], bfr[n], acc[m][n], 0, 0, 0);
    }
    WAITLGKM0;
    BARRIER();
  }
#undef G2_STAGE

  int brow = bm * 128, bcol = bn * 128;
  float rowpart[2][4] = {};                // [m][j]
#pragma unroll
  for (int n = 0; n < 4; ++n) {
    int cg = bcol + wc * 64 + n * 16 + (lane & 15);
    int d = cg >> 1;
    float bias = (cg & 1) ? bb[d] : ba[d];
    float wcd = Wc[d];
#pragma unroll
    for (int m = 0; m < 2; ++m)
#pragma unroll
      for (int j = 0; j < 4; ++j) {
        float v = acc[m][n][j] + bias;
        float av = (cg & 1) ? (1.f / (1.f + expf(-v))) : tanhf(v);
        float pv = av * __shfl_xor(av, 1, 64);
        rowpart[m][j] += pv * wcd;
      }
  }
#pragma unroll
  for (int m = 0; m < 2; ++m)
#pragma unroll
    for (int j = 0; j < 4; ++j) {
      float t = rowpart[m][j];
      t += __shfl_xor(t, 2, 64);
      t += __shfl_xor(t, 4, 64);
      t += __shfl_xor(t, 8, 64);
      rowpart[m][j] = t;
    }
  if ((lane & 15) == 0) {
    int slot = bn * 2 + wc;
#pragma unroll
    for (int m = 0; m < 2; ++m)
#pragma unroll
      for (int j = 0; j < 4; ++j) {
        int row = brow + wr * 32 + m * 16 + (lane >> 4) * 4 + j;
        A_part[(size_t)row * 8 + slot] = rowpart[m][j];
      }
  }
}

// ---------------- per-bag softmax (unchanged)
__global__ void carp_softmax(const float* __restrict__ A_part, const float* __restrict__ bc,
                             float* __restrict__ A_raw_out, float* __restrict__ A_sm) {
  __shared__ float sv[8192];
  __shared__ float red[256];
  int b = blockIdx.x, tid = threadIdx.x;
  float bcv = bc[0];
  float lmax = -1e30f;
  for (int i = tid; i < 8192; i += 256) {
    const float4* p = (const float4*)(A_part + (size_t)(b * 8192 + i) * 8);
    float4 x = p[0], y = p[1];
    float s = ((x.x + x.y) + (x.z + x.w)) + ((y.x + y.y) + (y.z + y.w)) + bcv;
    sv[i] = s;
    A_raw_out[b * 8192 + i] = s;
    lmax = fmaxf(lmax, s);
  }
  red[tid] = lmax;
  for (int s = 128; s > 0; s >>= 1) { __syncthreads(); if (tid < s) red[tid] = fmaxf(red[tid], red[tid + s]); }
  __syncthreads();
  float mx = red[0];
  __syncthreads();
  float lsum = 0.f;
  for (int i = tid; i < 8192; i += 256) {
    float e = expf(sv[i] - mx);
    sv[i] = e;
    lsum += e;
  }
  red[tid] = lsum;
  for (int s = 128; s > 0; s >>= 1) { __syncthreads(); if (tid < s) red[tid] += red[tid + s]; }
  __syncthreads();
  float inv = 1.f / red[0];
  for (int i = tid; i < 8192; i += 256) A_sm[b * 8192 + i] = sv[i] * inv;
}

// ---------------- M partials (unchanged, reads h1_pk granules)
__global__ void carp_mkernel(const unsigned short* __restrict__ h1_pk, const float* __restrict__ A_sm,
                             float* __restrict__ Mpart) {
  __shared__ float sw[128];
  int bm = blockIdx.x;
  int tid = threadIdx.x;
  if (tid < 128) sw[tid] = A_sm[bm * 128 + tid];
  __syncthreads();
  int l = tid & 63;
  float acc[4][8] = {};
#pragma unroll
  for (int tq = 0; tq < 4; ++tq) {
    int tt = (tid >> 6) * 4 + tq;
#pragma unroll
    for (int s = 0; s < 8; ++s) {
      const unsigned short* gp = h1_pk + ((size_t)(bm * 16 + tt) * 512 + s * 64 + l) * 8;
      uint4 raw = *(const uint4*)gp;
      const unsigned short* pv = (const unsigned short*)&raw;
      float w = sw[s * 16 + (l & 15)];
#pragma unroll
      for (int e = 0; e < 8; ++e) acc[tq][e] += w * bf2f(pv[e]);
    }
  }
#pragma unroll
  for (int tq = 0; tq < 4; ++tq)
#pragma unroll
    for (int e = 0; e < 8; ++e) {
      float t = acc[tq][e];
      t += __shfl_xor(t, 1, 64);
      t += __shfl_xor(t, 2, 64);
      t += __shfl_xor(t, 4, 64);
      t += __shfl_xor(t, 8, 64);
      acc[tq][e] = t;
    }
  if ((l & 15) == 0) {
    int cc = (l >> 4) & 3;
#pragma unroll
    for (int tq = 0; tq < 4; ++tq) {
      int tt = (tid >> 6) * 4 + tq;
      float* mp = Mpart + (size_t)bm * 512 + tt * 32 + cc * 8;
#pragma unroll
      for (int e = 0; e < 8; ++e) mp[e] = acc[tq][e];
    }
  }
}

// ---------------- final (unchanged)
__global__ void carp_final(const float* __restrict__ Mpart, const float* __restrict__ Wcls,
                           const float* __restrict__ bcls, float* __restrict__ out) {
  __shared__ float ctx[512];
  int t = threadIdx.x;
  float c = 0.f;
  for (int b = 0; b < 16; ++b) {
    float s = 0.f;
    for (int p = 0; p < 64; ++p) s += Mpart[((size_t)(b * 64 + p) << 9) + t];
    out[131077 + b * 512 + t] = s;
    c += s;
  }
  ctx[t] = c * (1.f / 16.f);
  __syncthreads();
  if (t < 64) {
    float p0 = 0.f, p1 = 0.f;
    for (int hh = t; hh < 512; hh += 64) {
      float cv = ctx[hh];
      p0 += cv * Wcls[hh * 2];
      p1 += cv * Wcls[hh * 2 + 1];
    }
    for (int m = 1; m < 64; m <<= 1) { p0 += __shfl_xor(p0, m, 64); p1 += __shfl_xor(p1, m, 64); }
    if (t == 0) {
      float l0 = p0 + bcls[0], l1 = p1 + bcls[1];
      out[0] = l0; out[1] = l1;
      float mx = fmaxf(l0, l1);
      float e0 = expf(l0 - mx), e1 = expf(l1 - mx);
      float s = e0 + e1;
      out[2] = e0 / s; out[3] = e1 / s;
      out[4] = (l1 > l0) ? 1.0f : 0.0f;
    }
  }
}

extern "C" void kernel_launch(void* const* d_in, const int* in_sizes, int n_in,
                              void* d_out, int out_size, void* d_ws, size_t ws_size,
                              hipStream_t stream) {
  const float* h    = (const float*)d_in[0];
  const float* W1   = (const float*)d_in[1];
  const float* b1   = (const float*)d_in[2];
  const float* Wa   = (const float*)d_in[3];
  const float* ba   = (const float*)d_in[4];
  const float* Wb   = (const float*)d_in[5];
  const float* bb   = (const float*)d_in[6];
  const float* Wc   = (const float*)d_in[7];
  const float* bc   = (const float*)d_in[8];
  const float* Wcls = (const float*)d_in[9];
  const float* bcls = (const float*)d_in[10];
  float* out = (float*)d_out;

  char* ws = (char*)d_ws;
  unsigned short* h1_pk   = (unsigned short*)(ws);                  // 134,217,728 B
  unsigned short* W1T_pk  = (unsigned short*)(ws + 134217728);      //     524,288 B
  unsigned short* WabT_pk = (unsigned short*)(ws + 134742016);      //     524,288 B
  float* A_part           = (float*)(ws + 135266304);               //   4,194,304 B
  float* A_sm             = (float*)(ws + 139460608);               //     524,288 B
  float* Mpart            = (float*)(ws + 135266304);               //   overlays A_part

  carp_wpack  <<<256,  256, 0, stream>>>(W1, Wa, Wb, W1T_pk, WabT_pk);
  carp_gemm1  <<<4096, 512, 0, stream>>>(h, W1T_pk, b1, h1_pk);
  carp_gemm2  <<<4096, 512, 0, stream>>>(h1_pk, WabT_pk, ba, bb, Wc, A_part);
  carp_softmax<<<16,   256, 0, stream>>>(A_part, bc, out + 5, A_sm);
  carp_mkernel<<<1024, 256, 0, stream>>>(h1_pk, A_sm, Mpart);
  carp_final  <<<1,    512, 0, stream>>>(Mpart, Wcls, bcls, out);
}